// Round 7
// baseline (29.593 us; speedup 1.0000x reference)
//
#include <hip/hip_runtime.h>

// Problem constants (match reference)
constexpr int B = 128, N = 900, C = 91, M = 100;
constexpr float ALPHA = 0.25f;
constexpr float W_CLASS = 2.0f;
constexpr float W_BBOX = 5.0f;
constexpr float W_GIOU = 2.0f;

constexpr int NBX  = 15;          // blocks in n per batch
constexpr int ROWS = N / NBX;     // 60 rows per block
constexpr int BLK  = 256;
constexpr int MQ   = M / 4;       // 25 output quads per row
constexpr int NGRP = 10;          // row-groups; 250 active threads
constexpr int KIT  = ROWS / NGRP; // 6 consecutive rows per thread

__global__ __launch_bounds__(BLK) void hungarian_cost_kernel(
    const float* __restrict__ logits,   // [B, N, C]
    const float* __restrict__ pboxes,   // [B, N, 4] cxcywh
    const int*   __restrict__ tlabels,  // [B, M]
    const float* __restrict__ tboxes,   // [B, M, 4] cxcywh
    float* __restrict__ out)            // [B, N, M]
{
    const int b   = blockIdx.y;
    const int n0  = blockIdx.x * ROWS;
    const int tid = threadIdx.x;

    const int mq   = tid % MQ;        // 0..24 (quad of m)
    const int rgrp = tid / MQ;        // 0..10
    if (rgrp >= NGRP) return;         // 6 idle threads; no barriers anywhere

    const int r0 = rgrp * KIT;        // first of 6 CONSECUTIVE rows for this thread

    // Thread-level base pointers: per-k strides are small constants that fold
    // into the 13-bit signed immediate offset of global_load/store.
    const float*  lb   = logits + ((size_t)b * N + n0 + r0) * C;              // stride C*4   = 364 B
    const float4* pbt  = reinterpret_cast<const float4*>(pboxes) + (size_t)b * N + n0 + r0;  // 16 B
    float4*       outt = reinterpret_cast<float4*>(out) + ((size_t)(b * N + n0 + r0)) * MQ + mq; // 400 B

    // ---- Labels first (gather addresses depend on them) ----
    const int4 l4 = reinterpret_cast<const int4*>(tlabels + (size_t)b * M)[mq];
    const int labj[4] = {l4.x, l4.y, l4.z, l4.w};

    // ---- Issue ALL hot loads up front: 6 pred-box float4 + 24 logit gathers ----
    float4 pv[KIT];
    float  xsv[KIT][4];
    #pragma unroll
    for (int k = 0; k < KIT; ++k) {
        pv[k] = pbt[k];
        #pragma unroll
        for (int j = 0; j < 4; ++j) xsv[k][j] = lb[k * C + labj[j]];
    }

    // ---- Targets -> registers: xyxy + area only (20 VGPR) ----
    float tx0[4], ty0[4], tx1[4], ty1[4], tar[4];
    {
        const float4* tbp = reinterpret_cast<const float4*>(tboxes) + (size_t)b * M;
        #pragma unroll
        for (int j = 0; j < 4; ++j) {
            const float4 t = tbp[mq * 4 + j];
            tx0[j] = t.x - 0.5f * t.z;  ty0[j] = t.y - 0.5f * t.w;
            tx1[j] = t.x + 0.5f * t.z;  ty1[j] = t.y + 0.5f * t.w;
            tar[j] = (tx1[j] - tx0[j]) * (ty1[j] - ty0[j]);
        }
    }

    // ---- Compute all 6 rows against in-flight loads ----
    #pragma unroll
    for (int k = 0; k < KIT; ++k) {
        const float4 p = pv[k];
        const float px0 = p.x - 0.5f * p.z, py0 = p.y - 0.5f * p.w;
        const float px1 = p.x + 0.5f * p.z, py1 = p.y + 0.5f * p.w;
        const float parea = (px1 - px0) * (py1 - py0);

        float4 res;
        float* rp = &res.x;
        #pragma unroll
        for (int j = 0; j < 4; ++j) {
            // focal class cost:  s = 1/(1+e), e = exp(-x)
            // -log(s) = log(1+e);  -log(1-s) = x + log(1+e)
            const float x    = xsv[k][j];
            const float e    = __expf(-x);
            const float onep = 1.0f + e;
            const float s    = __builtin_amdgcn_rcpf(onep);
            const float om   = e * s;            // 1 - s
            const float L    = __logf(onep);     // = -log(s)
            const float ccls = W_CLASS * (ALPHA * om * om * L
                                        - (1.0f - ALPHA) * s * s * (x + L));

            // L1 via xyxy deltas:
            // |pcx-tcx| = 0.5|dx0+dx1|,  |pw-tw| = |dx1-dx0|  (same for y)
            const float dx0 = px0 - tx0[j], dx1 = px1 - tx1[j];
            const float dy0 = py0 - ty0[j], dy1 = py1 - ty1[j];
            const float l1 = 0.5f * (fabsf(dx0 + dx1) + fabsf(dy0 + dy1))
                           + fabsf(dx1 - dx0) + fabsf(dy1 - dy0);

            // GIoU on xyxy, single reciprocal:
            // giou = (inter*earea - uni*(earea-uni)) / (uni*earea)
            const float iw = fmaxf(fminf(px1, tx1[j]) - fmaxf(px0, tx0[j]), 0.0f);
            const float ih = fmaxf(fminf(py1, ty1[j]) - fmaxf(py0, ty0[j]), 0.0f);
            const float inter = iw * ih;
            const float uni   = parea + tar[j] - inter;

            const float ew = fmaxf(px1, tx1[j]) - fminf(px0, tx0[j]);
            const float eh = fmaxf(py1, ty1[j]) - fminf(py0, ty0[j]);
            const float earea = ew * eh;

            const float num  = inter * earea - uni * (earea - uni);
            const float rcpD = __builtin_amdgcn_rcpf(uni * earea);

            rp[j] = ccls + W_BBOX * l1 - W_GIOU * (num * rcpD);
        }

        outt[(size_t)k * MQ] = res;   // byte stride 400: folds into imm offset
    }
}

extern "C" void kernel_launch(void* const* d_in, const int* in_sizes, int n_in,
                              void* d_out, int out_size, void* d_ws, size_t ws_size,
                              hipStream_t stream) {
    const float* logits  = (const float*)d_in[0];
    const float* pboxes  = (const float*)d_in[1];
    const int*   tlabels = (const int*)d_in[2];
    const float* tboxes  = (const float*)d_in[3];
    float* out = (float*)d_out;

    dim3 grid(NBX, B);
    dim3 block(BLK);
    hipLaunchKernelGGL(hungarian_cost_kernel, grid, block, 0, stream,
                       logits, pboxes, tlabels, tboxes, out);
}